// Round 9
// baseline (687.154 us; speedup 1.0000x reference)
//
#include <hip/hip_runtime.h>
#include <hip/hip_cooperative_groups.h>
#include <math.h>

namespace cg = cooperative_groups;

#define B_    2
#define T_    512
#define D_    512
#define E_    8
#define DI_   1024
#define DS_   16
#define DTR_  32
#define WIN_  64
#define BT_   (B_*T_)
#define BTD_  (BT_*D_)
#define NC_   16
#define LCH_  32    // T_/NC_

typedef unsigned short u16;
typedef __attribute__((ext_vector_type(8))) short bf16x8;
typedef __attribute__((ext_vector_type(4))) float f32x4;

// ---------- helpers ----------
__device__ __forceinline__ float gelu_f(float x) {
    float x3 = x * x * x;
    return 0.5f * x * (1.0f + tanhf(0.7978845608028654f * (x + 0.044715f * x3)));
}
__device__ __forceinline__ float silu_f(float x) {
    return x / (1.0f + __expf(-x));
}
__device__ __forceinline__ float softplus_f(float x) {
    return (x > 20.0f) ? x : log1pf(__expf(x));
}
__device__ __forceinline__ u16 f2bf(float x) {
    union { float f; unsigned u; } v; v.f = x;
    unsigned r = v.u + 0x7fffu + ((v.u >> 16) & 1u);
    return (u16)(r >> 16);
}
__device__ __forceinline__ float bf2f(u16 x) {
    union { unsigned u; float f; } v; v.u = ((unsigned)x) << 16; return v.f;
}
__device__ __forceinline__ void gload_lds16(const u16* g, u16* l) {
    __builtin_amdgcn_global_load_lds((const __attribute__((address_space(1))) void*)g,
                                     (__attribute__((address_space(3))) void*)l, 16, 0, 0);
}

// ---------- weight pool layout (elements) ----------
// region1 (fused-in): per e: cfi_e (1024x512) | min_e (2048x512); e-stride 1572864; total 6291456
// region2 (out): cfo (4x512x1024) | mow (4x512x1024); base 6291456; z-stride 524288
// region3: mxp (4x64x1024); base 10485760 (ends 10747904)
// region4: dw7t bf16 [z][j][c]: base 10747904, 28672
// region5: dw4t bf16 [z][j][c]: base 10776576, 16384 (ends 10792960)
#define DW7T_ 10747904
#define DW4T_ 10776576

// ======================================================================
// FRONT-END cooperative kernel: 512 blocks x 256 threads.
// Phase A: weight convert (grid-stride) + residual copy + proj/aux zero + rmsnorm
// Phase B: gating (blocks 0..255)
// Phase C: compaction + aux stats (blocks 0..7)
// ======================================================================
__global__ __launch_bounds__(256, 2) void frontend_kernel(
    const float* __restrict__ x, const float* __restrict__ nw,
    const float4* __restrict__ cfi, const float4* __restrict__ minw,
    const float4* __restrict__ cfo, const float4* __restrict__ mow4,
    const float4* __restrict__ mxp4, const float* __restrict__ cdw,
    const float* __restrict__ mcw, u16* __restrict__ wpool,
    const float* __restrict__ gw, const float* __restrict__ ew,
    const float* __restrict__ eb, const float* __restrict__ temp,
    float* __restrict__ xn, u16* __restrict__ xnb, float* __restrict__ v,
    float* __restrict__ wm, float* __restrict__ probs,
    int* __restrict__ idxl, int* __restrict__ cnt,
    float* __restrict__ out, float* __restrict__ proj)
{
    cg::grid_group grid = cg::this_grid();
    const int bid = blockIdx.x, tid = threadIdx.x;
    const int gtid = bid * 256 + tid;            // [0, 131072)

    // ---- phase A1: weight conversion, grid-stride ----
    for (int i = gtid; i < 2686976 + 45056; i += 512 * 256) {
        if (i < 2686976) {
            float4 val; size_t dg;
            if (i < 524288) {                    // cfi
                int e = i >> 17, r = i & 131071;
                val = cfi[i]; dg = (size_t)e * 393216 + r;
            } else if (i < 1572864) {            // min
                int off = i - 524288;
                int e = off >> 18, r = off & 262143;
                val = minw[off]; dg = (size_t)e * 393216 + 131072 + r;
            } else if (i < 2097152) {            // cfo
                val = cfo[i - 1572864]; dg = i;
            } else if (i < 2621440) {            // mow
                val = mow4[i - 2097152]; dg = i;
            } else {                             // mxp
                val = mxp4[i - 2621440]; dg = i;
            }
            ushort4 o;
            o.x = f2bf(val.x); o.y = f2bf(val.y); o.z = f2bf(val.z); o.w = f2bf(val.w);
            *(ushort4*)(wpool + dg * 4) = o;
        } else {
            int k = i - 2686976;
            if (k < 28672) {
                int z = k / 7168, r = k % 7168;
                int c = r / 7, j = r % 7;
                wpool[DW7T_ + z * 7168 + j * 1024 + c] = f2bf(cdw[k]);
            } else {
                int k2 = k - 28672;
                int z = k2 / 4096, r = k2 % 4096;
                int c = r / 4, j = r % 4;
                wpool[DW4T_ + z * 4096 + j * 1024 + c] = f2bf(mcw[k2]);
            }
        }
    }

    // ---- phase A2: residual copy (2 float2/thread), proj zero (2/thread), aux zero ----
    ((float2*)out)[gtid]          = ((const float2*)x)[gtid];
    ((float2*)out)[gtid + 131072] = ((const float2*)x)[gtid + 131072];
    proj[gtid] = 0.f;
    proj[gtid + 131072] = 0.f;
    if (gtid == 0) out[BTD_] = 0.f;

    // ---- phase A3: rmsnorm, 2 tokens per block ----
    __shared__ float sb[4], sb2[4];
    for (int rep = 0; rep < 2; ++rep) {
        int t = bid + rep * 512;
        const float* xr = x + (size_t)t * D_;
        float s = 0.f;
        for (int i = tid; i < D_; i += 256) { float a = xr[i]; s += a * a; }
        for (int o = 32; o > 0; o >>= 1) s += __shfl_down(s, o);
        if ((tid & 63) == 0) sb[tid >> 6] = s;
        __syncthreads();
        float tot = sb[0] + sb[1] + sb[2] + sb[3];
        float scale = rsqrtf(tot / (float)D_ + 1e-6f);
        float vs = 0.f;
        for (int i = tid; i < D_; i += 256) {
            float a = xr[i] * scale * nw[i];
            xn[(size_t)t * D_ + i] = a;
            xnb[(size_t)t * D_ + i] = f2bf(a);
            vs += a;
        }
        for (int o = 32; o > 0; o >>= 1) vs += __shfl_down(vs, o);
        if ((tid & 63) == 0) sb2[tid >> 6] = vs;
        __syncthreads();
        if (tid == 0) v[t] = (sb2[0] + sb2[1] + sb2[2] + sb2[3]) / (float)D_;
        __syncthreads();
    }

    grid.sync();

    // ---- phase B: gating, blocks 0..255, one wave per token ----
    if (bid < 256) {
        int wave = tid >> 6, lane = tid & 63;
        int t = bid * 4 + wave;
        int tloc = t & (T_ - 1);
        int base = t - tloc;
        int j = tloc - (WIN_ - 1) + lane;
        float vv = (j >= 0) ? v[base + j] : 0.f;
        float s1 = vv, s2 = vv * vv;
#pragma unroll
        for (int o = 32; o > 0; o >>= 1) { s1 += __shfl_down(s1, o); s2 += __shfl_down(s2, o); }
        const float* xr = xn + (size_t)t * D_;
        float l[E_];
#pragma unroll
        for (int e = 0; e < E_; ++e) {
            float s = 0.f;
            for (int i = lane; i < D_; i += 64) s += xr[i] * gw[e * D_ + i];
#pragma unroll
            for (int o = 32; o > 0; o >>= 1) s += __shfl_down(s, o);
            l[e] = s;
        }
        if (lane == 0) {
            float mu  = s1 / (float)WIN_;
            float mu2 = s2 / (float)WIN_;
            float var = fmaxf(mu2 - mu * mu, 0.f);
            float ev  = (logf(var + 1e-6f) + 10.f) / 20.f;
            float ts = 1.f / (fabsf(temp[0]) + 1e-6f);
#pragma unroll
            for (int e = 0; e < E_; ++e) l[e] = (l[e] + ev * ew[e] + eb[e]) * ts;
            int i1 = 0;
            for (int e = 1; e < E_; ++e) if (l[e] > l[i1]) i1 = e;
            int i2 = -1;
            for (int e = 0; e < E_; ++e) { if (e == i1) continue; if (i2 < 0 || l[e] > l[i2]) i2 = e; }
            float e2 = __expf(l[i2] - l[i1]);
            float Z = 1.f + e2;
#pragma unroll
            for (int e = 0; e < E_; ++e) wm[t * E_ + e] = 0.f;
            wm[t * E_ + i1] = 1.f / Z;
            wm[t * E_ + i2] = e2 / Z;
            float mm = l[0];
            for (int e = 1; e < E_; ++e) mm = fmaxf(mm, l[e]);
            float Zs = 0.f; float p[E_];
#pragma unroll
            for (int e = 0; e < E_; ++e) { p[e] = __expf(l[e] - mm); Zs += p[e]; }
#pragma unroll
            for (int e = 0; e < E_; ++e) probs[t * E_ + e] = p[e] / Zs;
        }
    }

    grid.sync();

    // ---- phase C: compaction + aux stats, blocks 0..7 ----
    if (bid < E_) {
        int e = bid;
        int wid = tid >> 6, lane = tid & 63;
        __shared__ int wsum[4];
        __shared__ int cbase;
        __shared__ float psum[4];
        if (tid == 0) cbase = 0;
        __syncthreads();
        float ps = 0.f;
        for (int chunk = 0; chunk < 4; ++chunk) {
            int t = chunk * 256 + tid;
            bool f = wm[t * E_ + e] > 0.f;
            ps += probs[t * E_ + e];
            unsigned long long m = __ballot(f);
            if (lane == 0) wsum[wid] = __popcll(m);
            __syncthreads();
            int off = cbase;
            for (int w = 0; w < wid; ++w) off += wsum[w];
            off += __popcll(m & ((1ull << lane) - 1ull));
            if (f) idxl[e * 1024 + off] = t;
            __syncthreads();
            if (tid == 0) cbase += wsum[0] + wsum[1] + wsum[2] + wsum[3];
            __syncthreads();
        }
#pragma unroll
        for (int o = 32; o > 0; o >>= 1) ps += __shfl_down(ps, o);
        if (lane == 0) psum[wid] = ps;
        __syncthreads();
        if (tid == 0) {
            cnt[e] = cbase;
            float pt = psum[0] + psum[1] + psum[2] + psum[3];
            atomicAdd(&out[BTD_], (float)E_ * ((float)cbase / (float)BT_) * (pt / (float)BT_));
        }
    }
}

// ======================================================================
// 64x64 MFMA GEMM kernels (BK=64, 4 waves of 2x2 16x16x32 frags)
// ======================================================================

// ---------- fused first GEMM: z=expert, nt<16 -> fc_in (gelu+bias -> hb),
//            nt>=16 -> in_proj (plain -> uzb). A = xnb (BT x 512), K=512. ----------
__global__ __launch_bounds__(256) void fused_in_gemm_kernel(
    const u16* __restrict__ xnb, const u16* __restrict__ wfused,
    const float* __restrict__ cfi_b, u16* __restrict__ hb, u16* __restrict__ uzb)
{
    const int z = blockIdx.z;
    const int nt = blockIdx.x;
    const bool isA = nt < 16;
    const int bn = (isA ? nt : nt - 16) * 64;
    const int bm = blockIdx.y * 64;
    const u16* A = xnb;
    const u16* W = wfused + (size_t)z * 1572864 + (isA ? 0 : 524288);

    __shared__ u16 As[64 * 64];
    __shared__ u16 Bs[64 * 64];
    const int tid  = threadIdx.x;
    const int wave = tid >> 6, lane = tid & 63;
    const int quad = lane >> 4, r16 = lane & 15;
    const int wm_ = (wave >> 1) * 32, wn = (wave & 1) * 32;

    const int s0 = tid, s1 = 256 + tid;
    const int r0 = s0 >> 3, q0 = (s0 & 7) ^ (r0 & 7);
    const int r1 = s1 >> 3, q1 = (s1 & 7) ^ (r1 & 7);
    const u16* Ag0 = A + (size_t)(bm + r0) * 512 + q0 * 8;
    const u16* Ag1 = A + (size_t)(bm + r1) * 512 + q1 * 8;
    const u16* Wg0 = W + (size_t)(bn + r0) * 512 + q0 * 8;
    const u16* Wg1 = W + (size_t)(bn + r1) * 512 + q1 * 8;

    f32x4 acc[2][2];
    const f32x4 zero = {0.f, 0.f, 0.f, 0.f};
    acc[0][0] = zero; acc[0][1] = zero; acc[1][0] = zero; acc[1][1] = zero;

    for (int k0 = 0; k0 < 512; k0 += 64) {
        gload_lds16(Ag0 + k0, As + tid * 8);
        gload_lds16(Ag1 + k0, As + (256 + tid) * 8);
        gload_lds16(Wg0 + k0, Bs + tid * 8);
        gload_lds16(Wg1 + k0, Bs + (256 + tid) * 8);
        __syncthreads();
#pragma unroll
        for (int ks = 0; ks < 2; ++ks) {
            bf16x8 af[2], bfr[2];
#pragma unroll
            for (int mi = 0; mi < 2; ++mi) {
                int row = wm_ + mi * 16 + r16;
                int p = (ks * 4 + quad) ^ (row & 7);
                af[mi] = *(const bf16x8*)(As + row * 64 + p * 8);
            }
#pragma unroll
            for (int ni = 0; ni < 2; ++ni) {
                int row = wn + ni * 16 + r16;
                int p = (ks * 4 + quad) ^ (row & 7);
                bfr[ni] = *(const bf16x8*)(Bs + row * 64 + p * 8);
            }
#pragma unroll
            for (int mi = 0; mi < 2; ++mi)
#pragma unroll
                for (int ni = 0; ni < 2; ++ni)
                    acc[mi][ni] = __builtin_amdgcn_mfma_f32_16x16x32_bf16(
                        af[mi], bfr[ni], acc[mi][ni], 0, 0, 0);
        }
        __syncthreads();
    }

#pragma unroll
    for (int mi = 0; mi < 2; ++mi) {
#pragma unroll
        for (int vv = 0; vv < 4; ++vv) {
            int m = bm + wm_ + mi * 16 + quad * 4 + vv;
#pragma unroll
            for (int ni = 0; ni < 2; ++ni) {
                int n = bn + wn + ni * 16 + r16;
                float val = acc[mi][ni][vv];
                if (isA) {
                    val = gelu_f(val + cfi_b[z * DI_ + n]);
                    hb[(size_t)z * BT_ * DI_ + (size_t)m * DI_ + n] = f2bf(val);
                } else {
                    uzb[(size_t)z * BT_ * 2048 + (size_t)m * 2048 + n] = f2bf(val);
                }
            }
        }
    }
}

// ---------- compacted output GEMM: z 0..7 (0-3 conv via gb, 4-7 mamba via yb) ----------
__global__ __launch_bounds__(256) void out_gemm_kernel(
    const u16* __restrict__ Ab, const u16* __restrict__ Wb,
    const float* __restrict__ cfo_b, float* __restrict__ out,
    const float* __restrict__ wmv, const int* __restrict__ idxl,
    const int* __restrict__ cnt)
{
    const int z = blockIdx.z;
    const int count = cnt[z];
    const int bm = blockIdx.y * 64;
    if (bm >= count) return;
    const int bn = blockIdx.x * 64;
    const u16* A = Ab + (size_t)z * BT_ * DI_;
    const u16* W = Wb + (size_t)z * 524288;
    const int* il = idxl + z * 1024;

    __shared__ u16 As[64 * 64];
    __shared__ u16 Bs[64 * 64];
    const int tid  = threadIdx.x;
    const int wave = tid >> 6, lane = tid & 63;
    const int quad = lane >> 4, r16 = lane & 15;
    const int wm_ = (wave >> 1) * 32, wn = (wave & 1) * 32;

    const int s0 = tid, s1 = 256 + tid;
    const int r0 = s0 >> 3, q0 = (s0 & 7) ^ (r0 & 7);
    const int r1 = s1 >> 3, q1 = (s1 & 7) ^ (r1 & 7);
    const int tok0 = il[min(bm + r0, count - 1)];
    const int tok1 = il[min(bm + r1, count - 1)];
    const u16* Ag0 = A + (size_t)tok0 * 1024 + q0 * 8;
    const u16* Ag1 = A + (size_t)tok1 * 1024 + q1 * 8;
    const u16* Wg0 = W + (size_t)(bn + r0) * 1024 + q0 * 8;
    const u16* Wg1 = W + (size_t)(bn + r1) * 1024 + q1 * 8;

    f32x4 acc[2][2];
    const f32x4 zero = {0.f, 0.f, 0.f, 0.f};
    acc[0][0] = zero; acc[0][1] = zero; acc[1][0] = zero; acc[1][1] = zero;

    for (int k0 = 0; k0 < 1024; k0 += 64) {
        gload_lds16(Ag0 + k0, As + tid * 8);
        gload_lds16(Ag1 + k0, As + (256 + tid) * 8);
        gload_lds16(Wg0 + k0, Bs + tid * 8);
        gload_lds16(Wg1 + k0, Bs + (256 + tid) * 8);
        __syncthreads();
#pragma unroll
        for (int ks = 0; ks < 2; ++ks) {
            bf16x8 af[2], bfr[2];
#pragma unroll
            for (int mi = 0; mi < 2; ++mi) {
                int row = wm_ + mi * 16 + r16;
                int p = (ks * 4 + quad) ^ (row & 7);
                af[mi] = *(const bf16x8*)(As + row * 64 + p * 8);
            }
#pragma unroll
            for (int ni = 0; ni < 2; ++ni) {
                int row = wn + ni * 16 + r16;
                int p = (ks * 4 + quad) ^ (row & 7);
                bfr[ni] = *(const bf16x8*)(Bs + row * 64 + p * 8);
            }
#pragma unroll
            for (int mi = 0; mi < 2; ++mi)
#pragma unroll
                for (int ni = 0; ni < 2; ++ni)
                    acc[mi][ni] = __builtin_amdgcn_mfma_f32_16x16x32_bf16(
                        af[mi], bfr[ni], acc[mi][ni], 0, 0, 0);
        }
        __syncthreads();
    }

#pragma unroll
    for (int mi = 0; mi < 2; ++mi) {
#pragma unroll
        for (int vv = 0; vv < 4; ++vv) {
            int mrow = bm + wm_ + mi * 16 + quad * 4 + vv;
            if (mrow >= count) continue;
            int tok = il[mrow];
            float wmval = wmv[tok * E_ + z];
#pragma unroll
            for (int ni = 0; ni < 2; ++ni) {
                int n = bn + wn + ni * 16 + r16;
                float val = acc[mi][ni][vv];
                if (z < 4) val += cfo_b[z * D_ + n];
                atomicAdd(&out[(size_t)tok * D_ + n], val * wmval);
            }
        }
    }
}

// ---------- 64x64 MFMA GEMM (xproj: N=64, split-K, fp32 atomic out) ----------
template<int SPLITK>
__global__ __launch_bounds__(256) void xproj_gemm_kernel(
    const u16* __restrict__ Ab, size_t sAe, int lda,
    const u16* __restrict__ Wb, size_t sWe, int ldw,
    float* __restrict__ Cp, size_t sCe, int ldc, int K)
{
    const int z = blockIdx.z / SPLITK;
    const int ks_ = blockIdx.z % SPLITK;
    const u16* A = Ab + (size_t)z * sAe;
    const u16* W = Wb + (size_t)z * sWe;

    __shared__ u16 As[64 * 64];
    __shared__ u16 Bs[64 * 64];
    const int tid  = threadIdx.x;
    const int wave = tid >> 6;
    const int lane = tid & 63;
    const int quad = lane >> 4;
    const int r16  = lane & 15;
    const int bm = blockIdx.y * 64;
    const int bn = blockIdx.x * 64;
    const int wm_ = (wave >> 1) * 32;
    const int wn = (wave & 1) * 32;

    const int s0 = tid, s1 = 256 + tid;
    const int r0 = s0 >> 3, q0 = (s0 & 7) ^ (r0 & 7);
    const int r1 = s1 >> 3, q1 = (s1 & 7) ^ (r1 & 7);
    const u16* Ag0 = A + (size_t)(bm + r0) * lda + q0 * 8;
    const u16* Ag1 = A + (size_t)(bm + r1) * lda + q1 * 8;
    const u16* Wg0 = W + (size_t)(bn + r0) * ldw + q0 * 8;
    const u16* Wg1 = W + (size_t)(bn + r1) * ldw + q1 * 8;

    f32x4 acc[2][2];
    const f32x4 zero = {0.f, 0.f, 0.f, 0.f};
    acc[0][0] = zero; acc[0][1] = zero; acc[1][0] = zero; acc[1][1] = zero;

    const int kBeg = ks_ * (K / SPLITK);
    const int kEnd = kBeg + K / SPLITK;
    for (int k0 = kBeg; k0 < kEnd; k0 += 64) {
        gload_lds16(Ag0 + k0, As + tid * 8);
        gload_lds16(Ag1 + k0, As + (256 + tid) * 8);
        gload_lds16(Wg0 + k0, Bs + tid * 8);
        gload_lds16(Wg1 + k0, Bs + (256 + tid) * 8);
        __syncthreads();
#pragma unroll
        for (int kss = 0; kss < 2; ++kss) {
            bf16x8 af[2], bfr[2];
#pragma unroll
            for (int mi = 0; mi < 2; ++mi) {
                int row = wm_ + mi * 16 + r16;
                int p = (kss * 4 + quad) ^ (row & 7);
                af[mi] = *(const bf16x8*)(As + row * 64 + p * 8);
            }
#pragma unroll
            for (int ni = 0; ni < 2; ++ni) {
                int row = wn + ni * 16 + r16;
                int p = (kss * 4 + quad) ^ (row & 7);
                bfr[ni] = *(const bf16x8*)(Bs + row * 64 + p * 8);
            }
#pragma unroll
            for (int mi = 0; mi < 2; ++mi)
#pragma unroll
                for (int ni = 0; ni < 2; ++ni)
                    acc[mi][ni] = __builtin_amdgcn_mfma_f32_16x16x32_bf16(
                        af[mi], bfr[ni], acc[mi][ni], 0, 0, 0);
        }
        __syncthreads();
    }

#pragma unroll
    for (int mi = 0; mi < 2; ++mi) {
#pragma unroll
        for (int vv = 0; vv < 4; ++vv) {
            int m = bm + wm_ + mi * 16 + quad * 4 + vv;
#pragma unroll
            for (int ni = 0; ni < 2; ++ni) {
                int n = bn + wn + ni * 16 + r16;
                atomicAdd(&(Cp + (size_t)z * sCe)[(size_t)m * ldc + n], acc[mi][ni][vv]);
            }
        }
    }
}

// ---------- fp32 GEMM for dt-proj (K=32), z-batched, softplus+bias ----------
__global__ __launch_bounds__(256) void dt_gemm_kernel(
    const float* __restrict__ proj, const float* __restrict__ dtw,
    const float* __restrict__ dtb, float* __restrict__ delta)
{
    const int z = blockIdx.z;
    const float* A = proj + (size_t)z * BT_ * 64;
    const float* W = dtw + (size_t)z * DI_ * DTR_;
    const float* bias = dtb + (size_t)z * DI_;
    float* C = delta + (size_t)z * BT_ * DI_;

    __shared__ float As[16][68];
    __shared__ float Ws[16][68];
    const int bm = blockIdx.y * 64, bn = blockIdx.x * 64;
    const int tid = threadIdx.x;
    const int tx = tid & 15, ty = tid >> 4;
    const int lm = tid >> 2, lk = (tid & 3) * 4;

    const float* Ap = A + (size_t)(bm + lm) * 64 + lk;
    const float* Wp = W + (size_t)(bn + lm) * DTR_ + lk;

    float acc[4][4] = {};
    for (int k0 = 0; k0 < DTR_; k0 += 16) {
        float4 av = *(const float4*)(Ap + k0);
        float4 wv = *(const float4*)(Wp + k0);
        __syncthreads();
        As[lk + 0][lm] = av.x; As[lk + 1][lm] = av.y;
        As[lk + 2][lm] = av.z; As[lk + 3][lm] = av.w;
        Ws[lk + 0][lm] = wv.x; Ws[lk + 1][lm] = wv.y;
        Ws[lk + 2][lm] = wv.z; Ws[lk + 3][lm] = wv.w;
        __syncthreads();
#pragma unroll
        for (int k = 0; k < 16; ++k) {
            float4 a = *(const float4*)&As[k][ty * 4];
            float4 w = *(const float4*)&Ws[k][tx * 4];
            acc[0][0] += a.x * w.x; acc[0][1] += a.x * w.y; acc[0][2] += a.x * w.z; acc[0][3] += a.x * w.w;
            acc[1][0] += a.y * w.x; acc[1][1] += a.y * w.y; acc[1][2] += a.y * w.z; acc[1][3] += a.y * w.w;
            acc[2][0] += a.z * w.x; acc[2][1] += a.z * w.y; acc[2][2] += a.z * w.z; acc[2][3] += a.z * w.w;
            acc[3][0] += a.w * w.x; acc[3][1] += a.w * w.y; acc[3][2] += a.w * w.z; acc[3][3] += a.w * w.w;
        }
    }
#pragma unroll
    for (int i = 0; i < 4; ++i) {
        int m = bm + ty * 4 + i;
#pragma unroll
        for (int j = 0; j < 4; ++j) {
            int n = bn + tx * 4 + j;
            C[(size_t)m * DI_ + n] = softplus_f(acc[i][j] + bias[n]);
        }
    }
}

// ---------- fused depthwise convs, 8 channels/thread, bf16x8 vector loads ----------
__global__ __launch_bounds__(256) void dwconv_fused_kernel(
    const u16* __restrict__ hb, const u16* __restrict__ w7t, const float* __restrict__ cb,
    u16* __restrict__ gb,
    const u16* __restrict__ uzb, const u16* __restrict__ w4t, const float* __restrict__ mb,
    u16* __restrict__ ucb)
{
    int idx = blockIdx.x * 256 + threadIdx.x;      // [0, 2 * 4*BT*128)
    if (idx < 4 * BT_ * 128) {
        int z = idx >> 17;
        int r = idx & 131071;
        int c8 = (r & 127) * 8;
        int bt = r >> 7;
        int t = bt & (T_ - 1);
        const u16* hp = hb + (size_t)z * BT_ * DI_ + (size_t)bt * DI_ + c8;
        const u16* wp = w7t + z * 7168 + c8;
        const float* bp = cb + z * DI_ + c8;
        float acc[8];
        float4 b0 = *(const float4*)bp;
        float4 b1 = *(const float4*)(bp + 4);
        acc[0] = b0.x; acc[1] = b0.y; acc[2] = b0.z; acc[3] = b0.w;
        acc[4] = b1.x; acc[5] = b1.y; acc[6] = b1.z; acc[7] = b1.w;
#pragma unroll
        for (int j = 0; j < 7; ++j) {
            int tt = t - 6 + j;
            if (tt >= 0) {
                bf16x8 hv = *(const bf16x8*)(hp + (j - 6) * DI_);
                bf16x8 wv = *(const bf16x8*)(wp + j * 1024);
#pragma unroll
                for (int k = 0; k < 8; ++k)
                    acc[k] += bf2f((u16)hv[k]) * bf2f((u16)wv[k]);
            }
        }
        u16 o[8];
#pragma unroll
        for (int k = 0; k < 8; ++k) o[k] = f2bf(gelu_f(acc[k]));
        *(bf16x8*)(gb + (size_t)z * BT_ * DI_ + (size_t)bt * DI_ + c8) = *(bf16x8*)o;
    } else {
        int i2 = idx - 4 * BT_ * 128;
        int z = i2 >> 17;
        int r = i2 & 131071;
        int c8 = (r & 127) * 8;
        int bt = r >> 7;
        int t = bt & (T_ - 1);
        const u16* up = uzb + (size_t)z * BT_ * 2048 + (size_t)bt * 2048 + c8;
        const u16* wp = w4t + z * 4096 + c8;
        const float* bp = mb + z * DI_ + c8;
        float acc[8];
        float4 b0 = *(const float4*)bp;
        float4 b1 = *(const float4*)(bp + 4);
        acc[0] = b0.x; acc[1] = b0.y; acc[2] = b0.z; acc[3] = b0.w;
        acc[4] = b1.x; acc[5] = b1.y; acc[6] = b1.z; acc[7] = b1.w;
#pragma unroll
        for (int j = 0; j < 4; ++j) {
            int tt = t - 3 + j;
            if (tt >= 0) {
                bf16x8 uv = *(const bf16x8*)(up + (j - 3) * 2048);
                bf16x8 wv = *(const bf16x8*)(wp + j * 1024);
#pragma unroll
                for (int k = 0; k < 8; ++k)
                    acc[k] += bf2f((u16)uv[k]) * bf2f((u16)wv[k]);
            }
        }
        u16 o[8];
#pragma unroll
        for (int k = 0; k < 8; ++k) o[k] = f2bf(silu_f(acc[k]));
        *(bf16x8*)(ucb + (size_t)z * BT_ * DI_ + (size_t)bt * DI_ + c8) = *(bf16x8*)o;
    }
}

// ======================================================================
// SCAN cooperative kernel: 512 blocks x 256 threads.
// pass1 (4 reps) -> sync -> mid (all 512 blocks) -> sync -> pass2 (4 reps)
// unit decomposition identical to the R7 scan1/scan_mid/scan2 kernels.
// ======================================================================
__global__ __launch_bounds__(256, 2) void scan_coop_kernel(
    const float* __restrict__ delta, const u16* __restrict__ uc,
    const float* __restrict__ proj, const float* __restrict__ Alog,
    const float* __restrict__ Dm, const u16* __restrict__ uz,
    float2* __restrict__ PH, float* __restrict__ H, u16* __restrict__ yb)
{
    cg::grid_group grid = cg::this_grid();

    // ---- pass 1 ----
    for (int rep = 0; rep < 4; ++rep) {
        int unit = blockIdx.x + rep * 512;          // 0..2047
        int z = unit >> 9;
        int idx = (unit & 511) * 256 + threadIdx.x;
        int sq = idx & 3;
        int d = (idx >> 2) & (DI_ - 1);
        int c = (idx >> 12) & (NC_ - 1);
        int b = idx >> 16;
        float A[4];
        *(float4*)A = *(const float4*)(Alog + (size_t)z * DI_ * DS_ + d * DS_ + sq * 4);
#pragma unroll
        for (int s = 0; s < 4; ++s) A[s] = -__expf(A[s]);
        int t0 = c * LCH_;
        const float* dp = delta + (size_t)z * BT_ * DI_ + ((size_t)b * T_ + t0) * DI_ + d;
        const u16*   up = uc    + (size_t)z * BT_ * DI_ + ((size_t)b * T_ + t0) * DI_ + d;
        const float* pp = proj  + (size_t)z * BT_ * 64 + ((size_t)b * T_ + t0) * 64 + 32 + sq * 4;
        float h[4] = {}, P[4] = {1.f, 1.f, 1.f, 1.f};
#pragma unroll 4
        for (int t = 0; t < LCH_; ++t) {
            float del = dp[(size_t)t * DI_];
            float uv  = bf2f(up[(size_t)t * DI_]);
            float du  = del * uv;
            float Bv[4];
            *(float4*)Bv = *(const float4*)(pp + t * 64);
#pragma unroll
            for (int s = 0; s < 4; ++s) {
                float dA = __expf(del * A[s]);
                h[s] = dA * h[s] + du * Bv[s];
                P[s] *= dA;
            }
        }
        float2* o = PH + (size_t)z * (B_ * NC_ * DI_ * 16)
                  + (size_t)(b * NC_ + c) * (DI_ * 16) + (size_t)d * 16 + sq * 4;
        float4 o0 = {P[0], h[0], P[1], h[1]};
        float4 o1 = {P[2], h[2], P[3], h[3]};
        *(float4*)&o[0] = o0;
        *(float4*)&o[2] = o1;
    }

    grid.sync();

    // ---- mid: inter-chunk recurrence ----
    {
        int gid = blockIdx.x * 256 + threadIdx.x;   // [0, 131072)
        int z = gid >> 15;
        int r = gid & 32767;
        int b = r >> 14;
        int ds16 = r & 16383;
        float h = 0.f;
        for (int c = 0; c < NC_; ++c) {
            size_t idx = (size_t)z * (B_ * NC_ * DI_ * 16) + ((size_t)(b * NC_ + c)) * (DI_ * 16) + ds16;
            H[idx] = h;
            float2 ph = PH[idx];
            h = ph.y + ph.x * h;
        }
    }

    grid.sync();

    // ---- pass 2 ----
    for (int rep = 0; rep < 4; ++rep) {
        int unit = blockIdx.x + rep * 512;
        int z = unit >> 9;
        int idx = (unit & 511) * 256 + threadIdx.x;
        int sq = idx & 3;
        int d = (idx >> 2) & (DI_ - 1);
        int c = (idx >> 12) & (NC_ - 1);
        int b = idx >> 16;
        float A[4];
        *(float4*)A = *(const float4*)(Alog + (size_t)z * DI_ * DS_ + d * DS_ + sq * 4);
#pragma unroll
        for (int s = 0; s < 4; ++s) A[s] = -__expf(A[s]);
        float Dd = Dm[(size_t)z * DI_ + d];
        float h[4];
        *(float4*)h = *(const float4*)(H + (size_t)z * (B_ * NC_ * DI_ * 16)
            + (size_t)(b * NC_ + c) * (DI_ * 16) + (size_t)d * 16 + sq * 4);
        int t0 = c * LCH_;
        const float* dp = delta + (size_t)z * BT_ * DI_ + ((size_t)b * T_ + t0) * DI_ + d;
        const u16*   up = uc    + (size_t)z * BT_ * DI_ + ((size_t)b * T_ + t0) * DI_ + d;
        const float* pp = proj  + (size_t)z * BT_ * 64 + ((size_t)b * T_ + t0) * 64 + 32 + sq * 4;
        const u16*   zp = uz    + (size_t)z * BT_ * 2048 + ((size_t)b * T_ + t0) * 2048 + DI_ + d;
        u16* yp = yb + (size_t)z * BT_ * DI_ + ((size_t)b * T_ + t0) * DI_ + d;
#pragma unroll 4
        for (int t = 0; t < LCH_; ++t) {
            float del = dp[(size_t)t * DI_];
            float uv  = bf2f(up[(size_t)t * DI_]);
            float du  = del * uv;
            float Bv[4], Cv[4];
            *(float4*)Bv = *(const float4*)(pp + t * 64);
            *(float4*)Cv = *(const float4*)(pp + t * 64 + 16);
            float y = 0.f;
#pragma unroll
            for (int s = 0; s < 4; ++s) {
                float dA = __expf(del * A[s]);
                h[s] = dA * h[s] + du * Bv[s];
                y += h[s] * Cv[s];
            }
            y += __shfl_down(y, 1, 4);
            y += __shfl_down(y, 2, 4);
            if (sq == 0) {
                y += uv * Dd;
                float zval = bf2f(zp[(size_t)t * 2048]);
                yp[(size_t)t * DI_] = f2bf(y * silu_f(zval));
            }
        }
    }
}

extern "C" void kernel_launch(void* const* d_in, const int* in_sizes, int n_in,
                              void* d_out, int out_size, void* d_ws, size_t ws_size,
                              hipStream_t stream)
{
    const float* x      = (const float*)d_in[0];
    const float* norm_w = (const float*)d_in[1];
    const float* gate_w = (const float*)d_in[2];
    const float* ent_w  = (const float*)d_in[3];
    const float* ent_b  = (const float*)d_in[4];
    const float* temp   = (const float*)d_in[5];
    const float* cfi_w  = (const float*)d_in[6];
    const float* cfi_b  = (const float*)d_in[7];
    const float* cdw_w  = (const float*)d_in[8];
    const float* cdw_b  = (const float*)d_in[9];
    const float* cfo_w  = (const float*)d_in[10];
    const float* cfo_b  = (const float*)d_in[11];
    const float* min_w  = (const float*)d_in[12];
    const float* mcw    = (const float*)d_in[13];
    const float* mcb    = (const float*)d_in[14];
    const float* mxp    = (const float*)d_in[15];
    const float* mdtw   = (const float*)d_in[16];
    const float* mdtb   = (const float*)d_in[17];
    const float* mAlog  = (const float*)d_in[18];
    const float* mD     = (const float*)d_in[19];
    const float* mow    = (const float*)d_in[20];

    float* out = (float*)d_out;

    char* wp = (char*)d_ws;
    auto alloc = [&](size_t bytes) { char* r = wp; wp += (bytes + 255) & ~(size_t)255; return r; };

    float* xn    = (float*)alloc((size_t)BTD_ * 4);
    u16*   xnb   = (u16*)  alloc((size_t)BTD_ * 2);
    float* v     = (float*)alloc(BT_ * 4);
    float* wm    = (float*)alloc(BT_ * E_ * 4);
    float* probs = (float*)alloc(BT_ * E_ * 4);
    int*   idxl  = (int*)  alloc(E_ * 1024 * 4);
    int*   cnt   = (int*)  alloc(E_ * 4);
    u16*   wpool = (u16*)  alloc((size_t)10792960 * 2);
    u16* wfused  = wpool;                    // 6291456 elems
    u16* wout    = wpool + 6291456;          // 4194304 elems (cfo | mow)
    u16* mxp_b16 = wpool + 10485760;         // 262144 elems
    u16* dw7t    = wpool + DW7T_;
    u16* dw4t    = wpool + DW4T_;

    char* pool = alloc((size_t)81 * 1024 * 1024);
    u16*    hb   = (u16*)pool;                                    // 8MB (dead after dwconv)
    u16*    gb   = (u16*)(pool + (size_t)8 * 1024 * 1024);        // 8MB
    u16*    yb   = (u16*)(pool + (size_t)16 * 1024 * 1024);       // 8MB (gb|yb contiguous)
    u16*    uzb  = (u16*)(pool + (size_t)24 * 1024 * 1024);       // 16MB
    u16*    ucb  = (u16*)(pool + (size_t)40 * 1024 * 1024);       // 8MB
    float*  proj = (float*)(pool + (size_t)48 * 1024 * 1024);     // 1MB
    float*  delta= (float*)(pool + (size_t)49 * 1024 * 1024);     // 16MB
    float2* sPH  = (float2*)(pool + (size_t)65 * 1024 * 1024);    // 16MB
    float*  sH   = (float*)hb;                                    // 8MB alias of hb

    // ---- front-end cooperative kernel (convert + residual + rmsnorm + gating + compact) ----
    {
        const float4* cfi4 = (const float4*)cfi_w;
        const float4* min4 = (const float4*)min_w;
        const float4* cfo4 = (const float4*)cfo_w;
        const float4* mow4 = (const float4*)mow;
        const float4* mxp4 = (const float4*)mxp;
        void* fa[] = { (void*)&x, (void*)&norm_w, (void*)&cfi4, (void*)&min4,
                       (void*)&cfo4, (void*)&mow4, (void*)&mxp4, (void*)&cdw_w,
                       (void*)&mcw, (void*)&wpool, (void*)&gate_w, (void*)&ent_w,
                       (void*)&ent_b, (void*)&temp, (void*)&xn, (void*)&xnb,
                       (void*)&v, (void*)&wm, (void*)&probs, (void*)&idxl,
                       (void*)&cnt, (void*)&out, (void*)&proj };
        hipLaunchCooperativeKernel((void*)frontend_kernel, dim3(512), dim3(256),
                                   fa, 0, stream);
    }

    // ---- fused first GEMM: fc_in (nt<16) + in_proj (nt>=16), 64x64 tiles ----
    fused_in_gemm_kernel<<<dim3(48, 16, 4), 256, 0, stream>>>(
        xnb, wfused, cfi_b, hb, uzb);

    // ---- fused depthwise convs (8 ch/thread, vectorized) ----
    dwconv_fused_kernel<<<2 * 4 * BT_ * 128 / 256, 256, 0, stream>>>(
        hb, dw7t, cdw_b, gb, uzb, dw4t, mcb, ucb);

    // ---- xproj (split-K=4, proj pre-zeroed by frontend) + dt ----
    xproj_gemm_kernel<4><<<dim3(1, BT_ / 64, 16), 256, 0, stream>>>(
        ucb, (size_t)BT_ * DI_, DI_, mxp_b16, (size_t)64 * DI_, DI_,
        proj, (size_t)BT_ * 64, 64, DI_);
    dt_gemm_kernel<<<dim3(DI_ / 64, BT_ / 64, 4), 256, 0, stream>>>(
        proj, mdtw, mdtb, delta);

    // ---- cooperative chunked scan (pass1 + mid + pass2) ----
    {
        void* sa[] = { (void*)&delta, (void*)&ucb, (void*)&proj, (void*)&mAlog,
                       (void*)&mD, (void*)&uzb, (void*)&sPH, (void*)&sH, (void*)&yb };
        hipLaunchCooperativeKernel((void*)scan_coop_kernel, dim3(512), dim3(256),
                                   sa, 0, stream);
    }

    // ---- compacted output GEMM: z 0..7 over gb|yb, gathered rows, atomic accumulate ----
    out_gemm_kernel<<<dim3(D_ / 64, BT_ / 64, 8), 256, 0, stream>>>(
        gb, wout, cfo_b, out, wm, idxl, cnt);
}

// Round 10
// 312.643 us; speedup vs baseline: 2.1979x; 2.1979x over previous
//
#include <hip/hip_runtime.h>
#include <math.h>

#define B_    2
#define T_    512
#define D_    512
#define E_    8
#define DI_   1024
#define DS_   16
#define DTR_  32
#define WIN_  64
#define BT_   (B_*T_)
#define BTD_  (BT_*D_)
#define NC_   16
#define LCH_  32    // T_/NC_

typedef unsigned short u16;
typedef __attribute__((ext_vector_type(8))) short bf16x8;
typedef __attribute__((ext_vector_type(4))) float f32x4;

// ---------- helpers ----------
__device__ __forceinline__ float gelu_f(float x) {
    float x3 = x * x * x;
    return 0.5f * x * (1.0f + tanhf(0.7978845608028654f * (x + 0.044715f * x3)));
}
__device__ __forceinline__ float silu_f(float x) {
    return x / (1.0f + __expf(-x));
}
__device__ __forceinline__ float softplus_f(float x) {
    return (x > 20.0f) ? x : log1pf(__expf(x));
}
__device__ __forceinline__ u16 f2bf(float x) {
    union { float f; unsigned u; } v; v.f = x;
    unsigned r = v.u + 0x7fffu + ((v.u >> 16) & 1u);
    return (u16)(r >> 16);
}
__device__ __forceinline__ float bf2f(u16 x) {
    union { unsigned u; float f; } v; v.u = ((unsigned)x) << 16; return v.f;
}
__device__ __forceinline__ void gload_lds16(const u16* g, u16* l) {
    __builtin_amdgcn_global_load_lds((const __attribute__((address_space(1))) void*)g,
                                     (__attribute__((address_space(3))) void*)l, 16, 0, 0);
}

// ---------- weight pool layout (elements) ----------
// region1 (fused-in): per e: cfi_e (1024x512) | min_e (2048x512); e-stride 1572864; total 6291456
// region2 (out): cfo (4x512x1024) | mow (4x512x1024); base 6291456; z-stride 524288
// region3: mxp (4x64x1024); base 10485760 (ends 10747904)
// region4: dw7t bf16 [z][j][c]: base 10747904, 28672
// region5: dw4t bf16 [z][j][c]: base 10776576, 16384 (ends 10792960)
#define DW7T_ 10747904
#define DW4T_ 10776576

// ======================================================================
// PREP kernel: 1024 blocks x 256 threads. All phases independent (no sync):
//  - weight conversion (grid-stride)
//  - residual copy out = x (float2/thread)
//  - proj zero + aux zero
//  - rmsnorm for token = blockIdx.x
// ======================================================================
__global__ __launch_bounds__(256) void prep_kernel(
    const float* __restrict__ x, const float* __restrict__ nw,
    const float4* __restrict__ cfi, const float4* __restrict__ minw,
    const float4* __restrict__ cfo, const float4* __restrict__ mow4,
    const float4* __restrict__ mxp4, const float* __restrict__ cdw,
    const float* __restrict__ mcw, u16* __restrict__ wpool,
    float* __restrict__ xn, u16* __restrict__ xnb, float* __restrict__ v,
    float* __restrict__ out, float* __restrict__ proj)
{
    const int bid = blockIdx.x, tid = threadIdx.x;
    const int gtid = bid * 256 + tid;            // [0, 262144)

    // weight conversion, grid-stride
    for (int i = gtid; i < 2686976 + 45056; i += 1024 * 256) {
        if (i < 2686976) {
            float4 val; size_t dg;
            if (i < 524288) {                    // cfi
                int e = i >> 17, r = i & 131071;
                val = cfi[i]; dg = (size_t)e * 393216 + r;
            } else if (i < 1572864) {            // min
                int off = i - 524288;
                int e = off >> 18, r = off & 262143;
                val = minw[off]; dg = (size_t)e * 393216 + 131072 + r;
            } else if (i < 2097152) {            // cfo
                val = cfo[i - 1572864]; dg = i;
            } else if (i < 2621440) {            // mow
                val = mow4[i - 2097152]; dg = i;
            } else {                             // mxp
                val = mxp4[i - 2621440]; dg = i;
            }
            ushort4 o;
            o.x = f2bf(val.x); o.y = f2bf(val.y); o.z = f2bf(val.z); o.w = f2bf(val.w);
            *(ushort4*)(wpool + dg * 4) = o;
        } else {
            int k = i - 2686976;
            if (k < 28672) {
                int z = k / 7168, r = k % 7168;
                int c = r / 7, j = r % 7;
                wpool[DW7T_ + z * 7168 + j * 1024 + c] = f2bf(cdw[k]);
            } else {
                int k2 = k - 28672;
                int z = k2 / 4096, r = k2 % 4096;
                int c = r / 4, j = r % 4;
                wpool[DW4T_ + z * 4096 + j * 1024 + c] = f2bf(mcw[k2]);
            }
        }
    }

    // residual copy (1 float2/thread) + proj zero + aux zero
    ((float2*)out)[gtid] = ((const float2*)x)[gtid];
    proj[gtid] = 0.f;
    if (gtid == 0) out[BTD_] = 0.f;

    // rmsnorm, token = bid
    __shared__ float sb[4], sb2[4];
    int t = bid;
    const float* xr = x + (size_t)t * D_;
    float s = 0.f;
    for (int i = tid; i < D_; i += 256) { float a = xr[i]; s += a * a; }
    for (int o = 32; o > 0; o >>= 1) s += __shfl_down(s, o);
    if ((tid & 63) == 0) sb[tid >> 6] = s;
    __syncthreads();
    float tot = sb[0] + sb[1] + sb[2] + sb[3];
    float scale = rsqrtf(tot / (float)D_ + 1e-6f);
    float vs = 0.f;
    for (int i = tid; i < D_; i += 256) {
        float a = xr[i] * scale * nw[i];
        xn[(size_t)t * D_ + i] = a;
        xnb[(size_t)t * D_ + i] = f2bf(a);
        vs += a;
    }
    for (int o = 32; o > 0; o >>= 1) vs += __shfl_down(vs, o);
    if ((tid & 63) == 0) sb2[tid >> 6] = vs;
    __syncthreads();
    if (tid == 0) v[t] = (sb2[0] + sb2[1] + sb2[2] + sb2[3]) / (float)D_;
}

// ---------- gating: one wave per token, entropy inline ----------
__global__ __launch_bounds__(256) void gating_kernel(
    const float* __restrict__ xn, const float* __restrict__ v,
    const float* __restrict__ gw, const float* __restrict__ ew,
    const float* __restrict__ eb, const float* __restrict__ temp,
    float* __restrict__ wm, float* __restrict__ probs)
{
    int wave = threadIdx.x >> 6, lane = threadIdx.x & 63;
    int t = blockIdx.x * 4 + wave;
    int tloc = t & (T_ - 1);
    int base = t - tloc;
    int j = tloc - (WIN_ - 1) + lane;
    float vv = (j >= 0) ? v[base + j] : 0.f;
    float s1 = vv, s2 = vv * vv;
#pragma unroll
    for (int o = 32; o > 0; o >>= 1) { s1 += __shfl_down(s1, o); s2 += __shfl_down(s2, o); }
    const float* xr = xn + (size_t)t * D_;
    float l[E_];
#pragma unroll
    for (int e = 0; e < E_; ++e) {
        float s = 0.f;
        for (int i = lane; i < D_; i += 64) s += xr[i] * gw[e * D_ + i];
#pragma unroll
        for (int o = 32; o > 0; o >>= 1) s += __shfl_down(s, o);
        l[e] = s;
    }
    if (lane == 0) {
        float mu  = s1 / (float)WIN_;
        float mu2 = s2 / (float)WIN_;
        float var = fmaxf(mu2 - mu * mu, 0.f);
        float ev  = (logf(var + 1e-6f) + 10.f) / 20.f;
        float ts = 1.f / (fabsf(temp[0]) + 1e-6f);
#pragma unroll
        for (int e = 0; e < E_; ++e) l[e] = (l[e] + ev * ew[e] + eb[e]) * ts;
        int i1 = 0;
        for (int e = 1; e < E_; ++e) if (l[e] > l[i1]) i1 = e;
        int i2 = -1;
        for (int e = 0; e < E_; ++e) { if (e == i1) continue; if (i2 < 0 || l[e] > l[i2]) i2 = e; }
        float e2 = __expf(l[i2] - l[i1]);
        float Z = 1.f + e2;
#pragma unroll
        for (int e = 0; e < E_; ++e) wm[t * E_ + e] = 0.f;
        wm[t * E_ + i1] = 1.f / Z;
        wm[t * E_ + i2] = e2 / Z;
        float mm = l[0];
        for (int e = 1; e < E_; ++e) mm = fmaxf(mm, l[e]);
        float Zs = 0.f; float p[E_];
#pragma unroll
        for (int e = 0; e < E_; ++e) { p[e] = __expf(l[e] - mm); Zs += p[e]; }
#pragma unroll
        for (int e = 0; e < E_; ++e) probs[t * E_ + e] = p[e] / Zs;
    }
}

// ---------- merged compaction + aux stats: one block per expert ----------
__global__ __launch_bounds__(256) void compact_stats_kernel(
    const float* __restrict__ wm, const float* __restrict__ probs,
    int* __restrict__ idxl, int* __restrict__ cnt, float* __restrict__ out_aux)
{
    int e = blockIdx.x;
    int tid = threadIdx.x;
    int wid = tid >> 6, lane = tid & 63;
    __shared__ int wsum[4];
    __shared__ int base;
    __shared__ float psum[4];
    if (tid == 0) base = 0;
    __syncthreads();
    float ps = 0.f;
    for (int chunk = 0; chunk < 4; ++chunk) {
        int t = chunk * 256 + tid;
        bool f = wm[t * E_ + e] > 0.f;
        ps += probs[t * E_ + e];
        unsigned long long m = __ballot(f);
        if (lane == 0) wsum[wid] = __popcll(m);
        __syncthreads();
        int off = base;
        for (int w = 0; w < wid; ++w) off += wsum[w];
        off += __popcll(m & ((1ull << lane) - 1ull));
        if (f) idxl[e * 1024 + off] = t;
        __syncthreads();
        if (tid == 0) base += wsum[0] + wsum[1] + wsum[2] + wsum[3];
        __syncthreads();
    }
#pragma unroll
    for (int o = 32; o > 0; o >>= 1) ps += __shfl_down(ps, o);
    if (lane == 0) psum[wid] = ps;
    __syncthreads();
    if (tid == 0) {
        cnt[e] = base;
        float pt = psum[0] + psum[1] + psum[2] + psum[3];
        atomicAdd(out_aux, (float)E_ * ((float)base / (float)BT_) * (pt / (float)BT_));
    }
}

// ======================================================================
// 64x64 MFMA GEMM kernels (BK=64, 4 waves of 2x2 16x16x32 frags)
// ======================================================================

// ---------- fused first GEMM: z=expert, nt<16 -> fc_in (gelu+bias -> hb),
//            nt>=16 -> in_proj (plain -> uzb). A = xnb (BT x 512), K=512. ----------
__global__ __launch_bounds__(256) void fused_in_gemm_kernel(
    const u16* __restrict__ xnb, const u16* __restrict__ wfused,
    const float* __restrict__ cfi_b, u16* __restrict__ hb, u16* __restrict__ uzb)
{
    const int z = blockIdx.z;
    const int nt = blockIdx.x;
    const bool isA = nt < 16;
    const int bn = (isA ? nt : nt - 16) * 64;
    const int bm = blockIdx.y * 64;
    const u16* A = xnb;
    const u16* W = wfused + (size_t)z * 1572864 + (isA ? 0 : 524288);

    __shared__ u16 As[64 * 64];
    __shared__ u16 Bs[64 * 64];
    const int tid  = threadIdx.x;
    const int wave = tid >> 6, lane = tid & 63;
    const int quad = lane >> 4, r16 = lane & 15;
    const int wm_ = (wave >> 1) * 32, wn = (wave & 1) * 32;

    const int s0 = tid, s1 = 256 + tid;
    const int r0 = s0 >> 3, q0 = (s0 & 7) ^ (r0 & 7);
    const int r1 = s1 >> 3, q1 = (s1 & 7) ^ (r1 & 7);
    const u16* Ag0 = A + (size_t)(bm + r0) * 512 + q0 * 8;
    const u16* Ag1 = A + (size_t)(bm + r1) * 512 + q1 * 8;
    const u16* Wg0 = W + (size_t)(bn + r0) * 512 + q0 * 8;
    const u16* Wg1 = W + (size_t)(bn + r1) * 512 + q1 * 8;

    f32x4 acc[2][2];
    const f32x4 zero = {0.f, 0.f, 0.f, 0.f};
    acc[0][0] = zero; acc[0][1] = zero; acc[1][0] = zero; acc[1][1] = zero;

    for (int k0 = 0; k0 < 512; k0 += 64) {
        gload_lds16(Ag0 + k0, As + tid * 8);
        gload_lds16(Ag1 + k0, As + (256 + tid) * 8);
        gload_lds16(Wg0 + k0, Bs + tid * 8);
        gload_lds16(Wg1 + k0, Bs + (256 + tid) * 8);
        __syncthreads();
#pragma unroll
        for (int ks = 0; ks < 2; ++ks) {
            bf16x8 af[2], bfr[2];
#pragma unroll
            for (int mi = 0; mi < 2; ++mi) {
                int row = wm_ + mi * 16 + r16;
                int p = (ks * 4 + quad) ^ (row & 7);
                af[mi] = *(const bf16x8*)(As + row * 64 + p * 8);
            }
#pragma unroll
            for (int ni = 0; ni < 2; ++ni) {
                int row = wn + ni * 16 + r16;
                int p = (ks * 4 + quad) ^ (row & 7);
                bfr[ni] = *(const bf16x8*)(Bs + row * 64 + p * 8);
            }
#pragma unroll
            for (int mi = 0; mi < 2; ++mi)
#pragma unroll
                for (int ni = 0; ni < 2; ++ni)
                    acc[mi][ni] = __builtin_amdgcn_mfma_f32_16x16x32_bf16(
                        af[mi], bfr[ni], acc[mi][ni], 0, 0, 0);
        }
        __syncthreads();
    }

#pragma unroll
    for (int mi = 0; mi < 2; ++mi) {
#pragma unroll
        for (int vv = 0; vv < 4; ++vv) {
            int m = bm + wm_ + mi * 16 + quad * 4 + vv;
#pragma unroll
            for (int ni = 0; ni < 2; ++ni) {
                int n = bn + wn + ni * 16 + r16;
                float val = acc[mi][ni][vv];
                if (isA) {
                    val = gelu_f(val + cfi_b[z * DI_ + n]);
                    hb[(size_t)z * BT_ * DI_ + (size_t)m * DI_ + n] = f2bf(val);
                } else {
                    uzb[(size_t)z * BT_ * 2048 + (size_t)m * 2048 + n] = f2bf(val);
                }
            }
        }
    }
}

// ---------- compacted output GEMM: z 0..7 (0-3 conv via gb, 4-7 mamba via yb) ----------
__global__ __launch_bounds__(256) void out_gemm_kernel(
    const u16* __restrict__ Ab, const u16* __restrict__ Wb,
    const float* __restrict__ cfo_b, float* __restrict__ out,
    const float* __restrict__ wmv, const int* __restrict__ idxl,
    const int* __restrict__ cnt)
{
    const int z = blockIdx.z;
    const int count = cnt[z];
    const int bm = blockIdx.y * 64;
    if (bm >= count) return;
    const int bn = blockIdx.x * 64;
    const u16* A = Ab + (size_t)z * BT_ * DI_;
    const u16* W = Wb + (size_t)z * 524288;
    const int* il = idxl + z * 1024;

    __shared__ u16 As[64 * 64];
    __shared__ u16 Bs[64 * 64];
    const int tid  = threadIdx.x;
    const int wave = tid >> 6, lane = tid & 63;
    const int quad = lane >> 4, r16 = lane & 15;
    const int wm_ = (wave >> 1) * 32, wn = (wave & 1) * 32;

    const int s0 = tid, s1 = 256 + tid;
    const int r0 = s0 >> 3, q0 = (s0 & 7) ^ (r0 & 7);
    const int r1 = s1 >> 3, q1 = (s1 & 7) ^ (r1 & 7);
    const int tok0 = il[min(bm + r0, count - 1)];
    const int tok1 = il[min(bm + r1, count - 1)];
    const u16* Ag0 = A + (size_t)tok0 * 1024 + q0 * 8;
    const u16* Ag1 = A + (size_t)tok1 * 1024 + q1 * 8;
    const u16* Wg0 = W + (size_t)(bn + r0) * 1024 + q0 * 8;
    const u16* Wg1 = W + (size_t)(bn + r1) * 1024 + q1 * 8;

    f32x4 acc[2][2];
    const f32x4 zero = {0.f, 0.f, 0.f, 0.f};
    acc[0][0] = zero; acc[0][1] = zero; acc[1][0] = zero; acc[1][1] = zero;

    for (int k0 = 0; k0 < 1024; k0 += 64) {
        gload_lds16(Ag0 + k0, As + tid * 8);
        gload_lds16(Ag1 + k0, As + (256 + tid) * 8);
        gload_lds16(Wg0 + k0, Bs + tid * 8);
        gload_lds16(Wg1 + k0, Bs + (256 + tid) * 8);
        __syncthreads();
#pragma unroll
        for (int ks = 0; ks < 2; ++ks) {
            bf16x8 af[2], bfr[2];
#pragma unroll
            for (int mi = 0; mi < 2; ++mi) {
                int row = wm_ + mi * 16 + r16;
                int p = (ks * 4 + quad) ^ (row & 7);
                af[mi] = *(const bf16x8*)(As + row * 64 + p * 8);
            }
#pragma unroll
            for (int ni = 0; ni < 2; ++ni) {
                int row = wn + ni * 16 + r16;
                int p = (ks * 4 + quad) ^ (row & 7);
                bfr[ni] = *(const bf16x8*)(Bs + row * 64 + p * 8);
            }
#pragma unroll
            for (int mi = 0; mi < 2; ++mi)
#pragma unroll
                for (int ni = 0; ni < 2; ++ni)
                    acc[mi][ni] = __builtin_amdgcn_mfma_f32_16x16x32_bf16(
                        af[mi], bfr[ni], acc[mi][ni], 0, 0, 0);
        }
        __syncthreads();
    }

#pragma unroll
    for (int mi = 0; mi < 2; ++mi) {
#pragma unroll
        for (int vv = 0; vv < 4; ++vv) {
            int mrow = bm + wm_ + mi * 16 + quad * 4 + vv;
            if (mrow >= count) continue;
            int tok = il[mrow];
            float wmval = wmv[tok * E_ + z];
#pragma unroll
            for (int ni = 0; ni < 2; ++ni) {
                int n = bn + wn + ni * 16 + r16;
                float val = acc[mi][ni][vv];
                if (z < 4) val += cfo_b[z * D_ + n];
                atomicAdd(&out[(size_t)tok * D_ + n], val * wmval);
            }
        }
    }
}

// ---------- 64x64 MFMA GEMM (xproj: N=64, split-K, fp32 atomic out) ----------
template<int SPLITK>
__global__ __launch_bounds__(256) void xproj_gemm_kernel(
    const u16* __restrict__ Ab, size_t sAe, int lda,
    const u16* __restrict__ Wb, size_t sWe, int ldw,
    float* __restrict__ Cp, size_t sCe, int ldc, int K)
{
    const int z = blockIdx.z / SPLITK;
    const int ks_ = blockIdx.z % SPLITK;
    const u16* A = Ab + (size_t)z * sAe;
    const u16* W = Wb + (size_t)z * sWe;

    __shared__ u16 As[64 * 64];
    __shared__ u16 Bs[64 * 64];
    const int tid  = threadIdx.x;
    const int wave = tid >> 6;
    const int lane = tid & 63;
    const int quad = lane >> 4;
    const int r16  = lane & 15;
    const int bm = blockIdx.y * 64;
    const int bn = blockIdx.x * 64;
    const int wm_ = (wave >> 1) * 32;
    const int wn = (wave & 1) * 32;

    const int s0 = tid, s1 = 256 + tid;
    const int r0 = s0 >> 3, q0 = (s0 & 7) ^ (r0 & 7);
    const int r1 = s1 >> 3, q1 = (s1 & 7) ^ (r1 & 7);
    const u16* Ag0 = A + (size_t)(bm + r0) * lda + q0 * 8;
    const u16* Ag1 = A + (size_t)(bm + r1) * lda + q1 * 8;
    const u16* Wg0 = W + (size_t)(bn + r0) * ldw + q0 * 8;
    const u16* Wg1 = W + (size_t)(bn + r1) * ldw + q1 * 8;

    f32x4 acc[2][2];
    const f32x4 zero = {0.f, 0.f, 0.f, 0.f};
    acc[0][0] = zero; acc[0][1] = zero; acc[1][0] = zero; acc[1][1] = zero;

    const int kBeg = ks_ * (K / SPLITK);
    const int kEnd = kBeg + K / SPLITK;
    for (int k0 = kBeg; k0 < kEnd; k0 += 64) {
        gload_lds16(Ag0 + k0, As + tid * 8);
        gload_lds16(Ag1 + k0, As + (256 + tid) * 8);
        gload_lds16(Wg0 + k0, Bs + tid * 8);
        gload_lds16(Wg1 + k0, Bs + (256 + tid) * 8);
        __syncthreads();
#pragma unroll
        for (int kss = 0; kss < 2; ++kss) {
            bf16x8 af[2], bfr[2];
#pragma unroll
            for (int mi = 0; mi < 2; ++mi) {
                int row = wm_ + mi * 16 + r16;
                int p = (kss * 4 + quad) ^ (row & 7);
                af[mi] = *(const bf16x8*)(As + row * 64 + p * 8);
            }
#pragma unroll
            for (int ni = 0; ni < 2; ++ni) {
                int row = wn + ni * 16 + r16;
                int p = (kss * 4 + quad) ^ (row & 7);
                bfr[ni] = *(const bf16x8*)(Bs + row * 64 + p * 8);
            }
#pragma unroll
            for (int mi = 0; mi < 2; ++mi)
#pragma unroll
                for (int ni = 0; ni < 2; ++ni)
                    acc[mi][ni] = __builtin_amdgcn_mfma_f32_16x16x32_bf16(
                        af[mi], bfr[ni], acc[mi][ni], 0, 0, 0);
        }
        __syncthreads();
    }

#pragma unroll
    for (int mi = 0; mi < 2; ++mi) {
#pragma unroll
        for (int vv = 0; vv < 4; ++vv) {
            int m = bm + wm_ + mi * 16 + quad * 4 + vv;
#pragma unroll
            for (int ni = 0; ni < 2; ++ni) {
                int n = bn + wn + ni * 16 + r16;
                atomicAdd(&(Cp + (size_t)z * sCe)[(size_t)m * ldc + n], acc[mi][ni][vv]);
            }
        }
    }
}

// ---------- fp32 GEMM for dt-proj (K=32), z-batched, softplus+bias ----------
__global__ __launch_bounds__(256) void dt_gemm_kernel(
    const float* __restrict__ proj, const float* __restrict__ dtw,
    const float* __restrict__ dtb, float* __restrict__ delta)
{
    const int z = blockIdx.z;
    const float* A = proj + (size_t)z * BT_ * 64;
    const float* W = dtw + (size_t)z * DI_ * DTR_;
    const float* bias = dtb + (size_t)z * DI_;
    float* C = delta + (size_t)z * BT_ * DI_;

    __shared__ float As[16][68];
    __shared__ float Ws[16][68];
    const int bm = blockIdx.y * 64, bn = blockIdx.x * 64;
    const int tid = threadIdx.x;
    const int tx = tid & 15, ty = tid >> 4;
    const int lm = tid >> 2, lk = (tid & 3) * 4;

    const float* Ap = A + (size_t)(bm + lm) * 64 + lk;
    const float* Wp = W + (size_t)(bn + lm) * DTR_ + lk;

    float acc[4][4] = {};
    for (int k0 = 0; k0 < DTR_; k0 += 16) {
        float4 av = *(const float4*)(Ap + k0);
        float4 wv = *(const float4*)(Wp + k0);
        __syncthreads();
        As[lk + 0][lm] = av.x; As[lk + 1][lm] = av.y;
        As[lk + 2][lm] = av.z; As[lk + 3][lm] = av.w;
        Ws[lk + 0][lm] = wv.x; Ws[lk + 1][lm] = wv.y;
        Ws[lk + 2][lm] = wv.z; Ws[lk + 3][lm] = wv.w;
        __syncthreads();
#pragma unroll
        for (int k = 0; k < 16; ++k) {
            float4 a = *(const float4*)&As[k][ty * 4];
            float4 w = *(const float4*)&Ws[k][tx * 4];
            acc[0][0] += a.x * w.x; acc[0][1] += a.x * w.y; acc[0][2] += a.x * w.z; acc[0][3] += a.x * w.w;
            acc[1][0] += a.y * w.x; acc[1][1] += a.y * w.y; acc[1][2] += a.y * w.z; acc[1][3] += a.y * w.w;
            acc[2][0] += a.z * w.x; acc[2][1] += a.z * w.y; acc[2][2] += a.z * w.z; acc[2][3] += a.z * w.w;
            acc[3][0] += a.w * w.x; acc[3][1] += a.w * w.y; acc[3][2] += a.w * w.z; acc[3][3] += a.w * w.w;
        }
    }
#pragma unroll
    for (int i = 0; i < 4; ++i) {
        int m = bm + ty * 4 + i;
#pragma unroll
        for (int j = 0; j < 4; ++j) {
            int n = bn + tx * 4 + j;
            C[(size_t)m * DI_ + n] = softplus_f(acc[i][j] + bias[n]);
        }
    }
}

// ---------- fused depthwise convs, 8 channels/thread, bf16x8 vector loads ----------
__global__ __launch_bounds__(256) void dwconv_fused_kernel(
    const u16* __restrict__ hb, const u16* __restrict__ w7t, const float* __restrict__ cb,
    u16* __restrict__ gb,
    const u16* __restrict__ uzb, const u16* __restrict__ w4t, const float* __restrict__ mb,
    u16* __restrict__ ucb)
{
    int idx = blockIdx.x * 256 + threadIdx.x;      // [0, 2 * 4*BT*128)
    if (idx < 4 * BT_ * 128) {
        int z = idx >> 17;
        int r = idx & 131071;
        int c8 = (r & 127) * 8;
        int bt = r >> 7;
        int t = bt & (T_ - 1);
        const u16* hp = hb + (size_t)z * BT_ * DI_ + (size_t)bt * DI_ + c8;
        const u16* wp = w7t + z * 7168 + c8;
        const float* bp = cb + z * DI_ + c8;
        float acc[8];
        float4 b0 = *(const float4*)bp;
        float4 b1 = *(const float4*)(bp + 4);
        acc[0] = b0.x; acc[1] = b0.y; acc[2] = b0.z; acc[3] = b0.w;
        acc[4] = b1.x; acc[5] = b1.y; acc[6] = b1.z; acc[7] = b1.w;
#pragma unroll
        for (int j = 0; j < 7; ++j) {
            int tt = t - 6 + j;
            if (tt >= 0) {
                bf16x8 hv = *(const bf16x8*)(hp + (j - 6) * DI_);
                bf16x8 wv = *(const bf16x8*)(wp + j * 1024);
#pragma unroll
                for (int k = 0; k < 8; ++k)
                    acc[k] += bf2f((u16)hv[k]) * bf2f((u16)wv[k]);
            }
        }
        u16 o[8];
#pragma unroll
        for (int k = 0; k < 8; ++k) o[k] = f2bf(gelu_f(acc[k]));
        *(bf16x8*)(gb + (size_t)z * BT_ * DI_ + (size_t)bt * DI_ + c8) = *(bf16x8*)o;
    } else {
        int i2 = idx - 4 * BT_ * 128;
        int z = i2 >> 17;
        int r = i2 & 131071;
        int c8 = (r & 127) * 8;
        int bt = r >> 7;
        int t = bt & (T_ - 1);
        const u16* up = uzb + (size_t)z * BT_ * 2048 + (size_t)bt * 2048 + c8;
        const u16* wp = w4t + z * 4096 + c8;
        const float* bp = mb + z * DI_ + c8;
        float acc[8];
        float4 b0 = *(const float4*)bp;
        float4 b1 = *(const float4*)(bp + 4);
        acc[0] = b0.x; acc[1] = b0.y; acc[2] = b0.z; acc[3] = b0.w;
        acc[4] = b1.x; acc[5] = b1.y; acc[6] = b1.z; acc[7] = b1.w;
#pragma unroll
        for (int j = 0; j < 4; ++j) {
            int tt = t - 3 + j;
            if (tt >= 0) {
                bf16x8 uv = *(const bf16x8*)(up + (j - 3) * 2048);
                bf16x8 wv = *(const bf16x8*)(wp + j * 1024);
#pragma unroll
                for (int k = 0; k < 8; ++k)
                    acc[k] += bf2f((u16)uv[k]) * bf2f((u16)wv[k]);
            }
        }
        u16 o[8];
#pragma unroll
        for (int k = 0; k < 8; ++k) o[k] = f2bf(silu_f(acc[k]));
        *(bf16x8*)(ucb + (size_t)z * BT_ * DI_ + (size_t)bt * DI_ + c8) = *(bf16x8*)o;
    }
}

// ---------- chunked selective scan: one thread per (b, chunk, d, s-quad) ----------
__global__ __launch_bounds__(256) void scan1_kernel(
    const float* __restrict__ delta, const u16* __restrict__ uc,
    const float* __restrict__ proj, const float* __restrict__ Alog,
    float2* __restrict__ PH)
{
    int z = blockIdx.y;
    int idx = blockIdx.x * 256 + threadIdx.x;
    int sq = idx & 3;
    int d = (idx >> 2) & (DI_ - 1);
    int c = (idx >> 12) & (NC_ - 1);
    int b = idx >> 16;
    float A[4];
    *(float4*)A = *(const float4*)(Alog + (size_t)z * DI_ * DS_ + d * DS_ + sq * 4);
#pragma unroll
    for (int s = 0; s < 4; ++s) A[s] = -__expf(A[s]);
    int t0 = c * LCH_;
    const float* dp = delta + (size_t)z * BT_ * DI_ + ((size_t)b * T_ + t0) * DI_ + d;
    const u16*   up = uc    + (size_t)z * BT_ * DI_ + ((size_t)b * T_ + t0) * DI_ + d;
    const float* pp = proj  + (size_t)z * BT_ * 64 + ((size_t)b * T_ + t0) * 64 + 32 + sq * 4;
    float h[4] = {}, P[4] = {1.f, 1.f, 1.f, 1.f};
#pragma unroll 4
    for (int t = 0; t < LCH_; ++t) {
        float del = dp[(size_t)t * DI_];
        float uv  = bf2f(up[(size_t)t * DI_]);
        float du  = del * uv;
        float Bv[4];
        *(float4*)Bv = *(const float4*)(pp + t * 64);
#pragma unroll
        for (int s = 0; s < 4; ++s) {
            float dA = __expf(del * A[s]);
            h[s] = dA * h[s] + du * Bv[s];
            P[s] *= dA;
        }
    }
    float2* o = PH + (size_t)z * (B_ * NC_ * DI_ * 16)
              + (size_t)(b * NC_ + c) * (DI_ * 16) + (size_t)d * 16 + sq * 4;
    float4 o0 = {P[0], h[0], P[1], h[1]};
    float4 o1 = {P[2], h[2], P[3], h[3]};
    *(float4*)&o[0] = o0;
    *(float4*)&o[2] = o1;
}

__global__ __launch_bounds__(256) void scan_mid_kernel(
    const float2* __restrict__ PH, float* __restrict__ H)
{
    int gid = blockIdx.x * 256 + threadIdx.x;   // (z, b, ds16)
    int z = gid >> 15;
    int r = gid & 32767;
    int b = r >> 14;
    int ds16 = r & 16383;
    float h = 0.f;
    for (int c = 0; c < NC_; ++c) {
        size_t idx = (size_t)z * (B_ * NC_ * DI_ * 16) + ((size_t)(b * NC_ + c)) * (DI_ * 16) + ds16;
        H[idx] = h;
        float2 ph = PH[idx];
        h = ph.y + ph.x * h;
    }
}

__global__ __launch_bounds__(256) void scan2_kernel(
    const float* __restrict__ delta, const u16* __restrict__ uc,
    const float* __restrict__ proj, const float* __restrict__ Alog,
    const float* __restrict__ Dm, const float* __restrict__ H,
    const u16* __restrict__ uz, u16* __restrict__ yb)
{
    int z = blockIdx.y;
    int idx = blockIdx.x * 256 + threadIdx.x;
    int sq = idx & 3;
    int d = (idx >> 2) & (DI_ - 1);
    int c = (idx >> 12) & (NC_ - 1);
    int b = idx >> 16;
    float A[4];
    *(float4*)A = *(const float4*)(Alog + (size_t)z * DI_ * DS_ + d * DS_ + sq * 4);
#pragma unroll
    for (int s = 0; s < 4; ++s) A[s] = -__expf(A[s]);
    float Dd = Dm[(size_t)z * DI_ + d];
    float h[4];
    *(float4*)h = *(const float4*)(H + (size_t)z * (B_ * NC_ * DI_ * 16)
        + (size_t)(b * NC_ + c) * (DI_ * 16) + (size_t)d * 16 + sq * 4);
    int t0 = c * LCH_;
    const float* dp = delta + (size_t)z * BT_ * DI_ + ((size_t)b * T_ + t0) * DI_ + d;
    const u16*   up = uc    + (size_t)z * BT_ * DI_ + ((size_t)b * T_ + t0) * DI_ + d;
    const float* pp = proj  + (size_t)z * BT_ * 64 + ((size_t)b * T_ + t0) * 64 + 32 + sq * 4;
    const u16*   zp = uz    + (size_t)z * BT_ * 2048 + ((size_t)b * T_ + t0) * 2048 + DI_ + d;
    u16* yp = yb + (size_t)z * BT_ * DI_ + ((size_t)b * T_ + t0) * DI_ + d;
#pragma unroll 4
    for (int t = 0; t < LCH_; ++t) {
        float del = dp[(size_t)t * DI_];
        float uv  = bf2f(up[(size_t)t * DI_]);
        float du  = del * uv;
        float Bv[4], Cv[4];
        *(float4*)Bv = *(const float4*)(pp + t * 64);
        *(float4*)Cv = *(const float4*)(pp + t * 64 + 16);
        float y = 0.f;
#pragma unroll
        for (int s = 0; s < 4; ++s) {
            float dA = __expf(del * A[s]);
            h[s] = dA * h[s] + du * Bv[s];
            y += h[s] * Cv[s];
        }
        y += __shfl_down(y, 1, 4);
        y += __shfl_down(y, 2, 4);
        if (sq == 0) {
            y += uv * Dd;
            float zval = bf2f(zp[(size_t)t * 2048]);
            yp[(size_t)t * DI_] = f2bf(y * silu_f(zval));
        }
    }
}

extern "C" void kernel_launch(void* const* d_in, const int* in_sizes, int n_in,
                              void* d_out, int out_size, void* d_ws, size_t ws_size,
                              hipStream_t stream)
{
    const float* x      = (const float*)d_in[0];
    const float* norm_w = (const float*)d_in[1];
    const float* gate_w = (const float*)d_in[2];
    const float* ent_w  = (const float*)d_in[3];
    const float* ent_b  = (const float*)d_in[4];
    const float* temp   = (const float*)d_in[5];
    const float* cfi_w  = (const float*)d_in[6];
    const float* cfi_b  = (const float*)d_in[7];
    const float* cdw_w  = (const float*)d_in[8];
    const float* cdw_b  = (const float*)d_in[9];
    const float* cfo_w  = (const float*)d_in[10];
    const float* cfo_b  = (const float*)d_in[11];
    const float* min_w  = (const float*)d_in[12];
    const float* mcw    = (const float*)d_in[13];
    const float* mcb    = (const float*)d_in[14];
    const float* mxp    = (const float*)d_in[15];
    const float* mdtw   = (const float*)d_in[16];
    const float* mdtb   = (const float*)d_in[17];
    const float* mAlog  = (const float*)d_in[18];
    const float* mD     = (const float*)d_in[19];
    const float* mow    = (const float*)d_in[20];

    float* out = (float*)d_out;

    char* wp = (char*)d_ws;
    auto alloc = [&](size_t bytes) { char* r = wp; wp += (bytes + 255) & ~(size_t)255; return r; };

    float* xn    = (float*)alloc((size_t)BTD_ * 4);
    u16*   xnb   = (u16*)  alloc((size_t)BTD_ * 2);
    float* v     = (float*)alloc(BT_ * 4);
    float* wm    = (float*)alloc(BT_ * E_ * 4);
    float* probs = (float*)alloc(BT_ * E_ * 4);
    int*   idxl  = (int*)  alloc(E_ * 1024 * 4);
    int*   cnt   = (int*)  alloc(E_ * 4);
    u16*   wpool = (u16*)  alloc((size_t)10792960 * 2);
    u16* wfused  = wpool;                    // 6291456 elems
    u16* wout    = wpool + 6291456;          // 4194304 elems (cfo | mow)
    u16* mxp_b16 = wpool + 10485760;         // 262144 elems
    u16* dw7t    = wpool + DW7T_;
    u16* dw4t    = wpool + DW4T_;

    char* pool = alloc((size_t)81 * 1024 * 1024);
    u16*    hb   = (u16*)pool;                                    // 8MB (dead after dwconv)
    u16*    gb   = (u16*)(pool + (size_t)8 * 1024 * 1024);        // 8MB
    u16*    yb   = (u16*)(pool + (size_t)16 * 1024 * 1024);       // 8MB (gb|yb contiguous)
    u16*    uzb  = (u16*)(pool + (size_t)24 * 1024 * 1024);       // 16MB
    u16*    ucb  = (u16*)(pool + (size_t)40 * 1024 * 1024);       // 8MB
    float*  proj = (float*)(pool + (size_t)48 * 1024 * 1024);     // 1MB
    float*  delta= (float*)(pool + (size_t)49 * 1024 * 1024);     // 16MB
    float2* sPH  = (float2*)(pool + (size_t)65 * 1024 * 1024);    // 16MB
    float*  sH   = (float*)hb;                                    // 8MB alias of hb

    // ---- prep: weight convert + residual copy + proj/aux zero + rmsnorm ----
    prep_kernel<<<BT_, 256, 0, stream>>>(
        x, norm_w, (const float4*)cfi_w, (const float4*)min_w, (const float4*)cfo_w,
        (const float4*)mow, (const float4*)mxp, cdw_w, mcw, wpool,
        xn, xnb, v, out, proj);

    gating_kernel<<<BT_ / 4, 256, 0, stream>>>(xn, v, gate_w, ent_w, ent_b, temp, wm, probs);
    compact_stats_kernel<<<E_, 256, 0, stream>>>(wm, probs, idxl, cnt, out + BTD_);

    // ---- fused first GEMM: fc_in (nt<16) + in_proj (nt>=16), 64x64 tiles ----
    fused_in_gemm_kernel<<<dim3(48, 16, 4), 256, 0, stream>>>(
        xnb, wfused, cfi_b, hb, uzb);

    // ---- fused depthwise convs (8 ch/thread, vectorized) ----
    dwconv_fused_kernel<<<2 * 4 * BT_ * 128 / 256, 256, 0, stream>>>(
        hb, dw7t, cdw_b, gb, uzb, dw4t, mcb, ucb);

    // ---- xproj (split-K=4, proj pre-zeroed by prep) + dt ----
    xproj_gemm_kernel<4><<<dim3(1, BT_ / 64, 16), 256, 0, stream>>>(
        ucb, (size_t)BT_ * DI_, DI_, mxp_b16, (size_t)64 * DI_, DI_,
        proj, (size_t)BT_ * 64, 64, DI_);
    dt_gemm_kernel<<<dim3(DI_ / 64, BT_ / 64, 4), 256, 0, stream>>>(
        proj, mdtw, mdtb, delta);

    // ---- chunked scan (full grids, separate dispatches) ----
    const int NSC = B_ * NC_ * DI_ * 4 / 256;  // 512 blocks/expert
    scan1_kernel<<<dim3(NSC, 4), 256, 0, stream>>>(delta, ucb, proj, mAlog, sPH);
    scan_mid_kernel<<<4 * B_ * DI_ * 16 / 256, 256, 0, stream>>>(sPH, sH);
    scan2_kernel<<<dim3(NSC, 4), 256, 0, stream>>>(
        delta, ucb, proj, mAlog, mD, sH, uzb, yb);

    // ---- compacted output GEMM: z 0..7 over gb|yb, gathered rows, atomic accumulate ----
    out_gemm_kernel<<<dim3(D_ / 64, BT_ / 64, 8), 256, 0, stream>>>(
        gb, wout, cfo_b, out, wm, idxl, cnt);
}